// Round 7
// baseline (415.111 us; speedup 1.0000x reference)
//
#include <hip/hip_runtime.h>
#include <hip/hip_fp16.h>
#include <math.h>

#define N_ 50000
#define E_ 640000
#define H_ 128
#define L_ 3
#define G_ 256
#define C_ 10
#define NEG_SLOPE 0.2f

#define SCAN_B 256
#define NBLK ((N_ + SCAN_B - 1) / SCAN_B)   // 196
#define ABLK ((N_ + 3) / 4)                 // 12500 (4 nodes per block)

typedef _Float16 half8 __attribute__((ext_vector_type(8)));
typedef float f32x4 __attribute__((ext_vector_type(4)));

__device__ __forceinline__ float leaky(float x) { return x > 0.f ? x : NEG_SLOPE * x; }

// ---------------- utility ----------------
__global__ void zero_i32(int* __restrict__ p, int n) {
    int i = blockIdx.x * blockDim.x + threadIdx.x;
    if (i < n) p[i] = 0;
}

// ---------------- CSR build ----------------
__global__ void count_deg(const int* __restrict__ dst, int* __restrict__ cnt) {
    int i = blockIdx.x * blockDim.x + threadIdx.x;
    if (i < E_) atomicAdd(&cnt[dst[i]], 1);
}

__global__ __launch_bounds__(SCAN_B) void scan_block(const int* __restrict__ cnt,
                                                     int* __restrict__ rowptr,
                                                     int* __restrict__ bsums) {
    int tid = threadIdx.x;
    int gid = blockIdx.x * SCAN_B + tid;
    int v = (gid < N_) ? cnt[gid] : 0;
    int lane = tid & 63, wid = tid >> 6;
    int x = v;
#pragma unroll
    for (int o = 1; o < 64; o <<= 1) {
        int t = __shfl_up(x, o);
        if (lane >= o) x += t;
    }
    __shared__ int wsum[4];
    if (lane == 63) wsum[wid] = x;
    __syncthreads();
    int woff = 0;
    for (int i = 0; i < wid; i++) woff += wsum[i];
    int incl = x + woff;
    if (gid < N_) rowptr[gid] = incl - v;            // exclusive within block
    if (tid == SCAN_B - 1) bsums[blockIdx.x] = incl; // block total
}

__global__ __launch_bounds__(256) void scan_bsums(int* __restrict__ bsums, int nb) {
    int tid = threadIdx.x;
    int v = (tid < nb) ? bsums[tid] : 0;
    int lane = tid & 63, wid = tid >> 6;
    int x = v;
#pragma unroll
    for (int o = 1; o < 64; o <<= 1) {
        int t = __shfl_up(x, o);
        if (lane >= o) x += t;
    }
    __shared__ int wsum[4];
    if (lane == 63) wsum[wid] = x;
    __syncthreads();
    int woff = 0;
    for (int i = 0; i < wid; i++) woff += wsum[i];
    if (tid < nb) bsums[tid] = x + woff - v;         // exclusive
}

__global__ __launch_bounds__(SCAN_B) void add_offsets(int* __restrict__ rowptr,
                                                      const int* __restrict__ bsums) {
    int gid = blockIdx.x * SCAN_B + threadIdx.x;
    if (gid < N_) rowptr[gid] += bsums[blockIdx.x];
    if (gid == 0) rowptr[N_] = E_;
}

__global__ void fill_csr(const int* __restrict__ src, const int* __restrict__ dst,
                         const int* __restrict__ rowptr, int* __restrict__ cur,
                         int* __restrict__ col) {
    int i = blockIdx.x * blockDim.x + threadIdx.x;
    if (i < E_) {
        int d = dst[i];
        int p = atomicAdd(&cur[d], 1);
        col[rowptr[d] + p] = src[i];
    }
}

// ---------------- weight prep: Wt[l][144][128] fp16 ----------------
// rows 0..127: W^T; row 128: W@a_src; row 129: W@a_dst; rows 130..143: zero.
__global__ __launch_bounds__(256) void prep_weights(const float* __restrict__ Wc,
                                                    const float* __restrict__ a_src,
                                                    const float* __restrict__ a_dst,
                                                    __half* __restrict__ Wt) {
    int l = blockIdx.x;
    const float* W = Wc + l * 16384;
    __half* T = Wt + (size_t)l * 144 * 128;
    int t = threadIdx.x;
    for (int e = t; e < 16384; e += 256) {
        int k = e >> 7, n = e & 127;
        T[n * 128 + k] = __float2half(W[e]);
    }
    if (t < 128) {
        int k = t;
        const float* as = a_src + l * 128;
        const float* ad = a_dst + l * 128;
        float s = 0.f, d = 0.f;
#pragma unroll 8
        for (int n = 0; n < 128; n++) {
            float w = W[k * 128 + n];
            s += w * as[n];
            d += w * ad[n];
        }
        T[128 * 128 + k] = __float2half(s);
        T[129 * 128 + k] = __float2half(d);
    } else {
        int kk = t - 128;
        for (int r = 130; r < 144; r++) T[r * 128 + kk] = __float2half(0.f);
    }
}

// ---------------- MFMA GEMM: h16c = fp16(A @ W) chunked, es/ed fused ----------------
// block = 256 threads (4 waves), BM=64 rows, N=128(+16) cols, K=128.
// h16 output layout: [4 chunks][N][32] (chunk c = features c*32..c*32+31).
// LDS XOR-swizzled (byte ^= (row&7)<<4) for conflict-free ds_read_b128.
template <bool FP16IN>
__global__ __launch_bounds__(256) void gemm_mfma(const void* __restrict__ Av,
                                                 const __half* __restrict__ Wt,
                                                 __half* __restrict__ h16,
                                                 float* __restrict__ es,
                                                 float* __restrict__ ed) {
    __shared__ __half Asw[64 * 128];    // 16 KB
    __shared__ __half Bsw[144 * 128];   // 36 KB
    int tid = threadIdx.x;
    int brow = blockIdx.x * 64;

    // --- stage A (swizzled) ---
    {
        int r = tid >> 2;             // 0..63
        int q = tid & 3;              // k-chunk 0..3 (32 elems)
        int grow = brow + r;
        if (FP16IN) {
            // chunked fp16 input: [4][N][32]
            const __half* Ah = (const __half*)Av;
            float4 vv[4];
            if (grow < N_) {
                const float4* p = (const float4*)(Ah + ((size_t)q * N_ + grow) * 32);
#pragma unroll
                for (int s = 0; s < 4; s++) vv[s] = p[s];
            } else {
                float4 zz = make_float4(0.f, 0.f, 0.f, 0.f);
#pragma unroll
                for (int s = 0; s < 4; s++) vv[s] = zz;
            }
#pragma unroll
            for (int s = 0; s < 4; s++) {
                int kbyte = q * 64 + s * 16;
                int addr = r * 256 + (kbyte ^ ((r & 7) << 4));
                *(float4*)((char*)Asw + addr) = vv[s];
            }
        } else {
            const float* A = (const float*)Av;
            int kc = q * 32;
            float v[32];
            if (grow < N_) {
                const float4* p = (const float4*)(A + (size_t)grow * 128 + kc);
#pragma unroll
                for (int s = 0; s < 8; s++) {
                    float4 f = p[s];
                    v[s * 4] = f.x; v[s * 4 + 1] = f.y; v[s * 4 + 2] = f.z; v[s * 4 + 3] = f.w;
                }
            } else {
#pragma unroll
                for (int s = 0; s < 32; s++) v[s] = 0.f;
            }
#pragma unroll
            for (int s = 0; s < 4; s++) {
                half8 h;
#pragma unroll
                for (int j = 0; j < 8; j++) h[j] = (_Float16)v[s * 8 + j];
                int kbyte = kc * 2 + s * 16;
                int addr = r * 256 + (kbyte ^ ((r & 7) << 4));
                *(half8*)((char*)Asw + addr) = h;
            }
        }
    }
    // --- stage B: linear fp16 copy, swizzled (2304 16B chunks) ---
    {
        const float4* src = (const float4*)Wt;
#pragma unroll
        for (int i = 0; i < 9; i++) {
            int c = tid + i * 256;
            int o = c * 16;
            int n = o >> 8;
            float4 val = src[c];
            int addr = n * 256 + ((o & 255) ^ ((n & 7) << 4));
            *(float4*)((char*)Bsw + addr) = val;
        }
    }
    __syncthreads();

    // --- MFMA: wave w -> rows w*16..+15, 9 n-tiles, 4 k-steps ---
    int w = tid >> 6, l = tid & 63;
    int lrow = l & 15, lk = l >> 4;
    f32x4 acc[9];
#pragma unroll
    for (int t = 0; t < 9; t++) acc[t] = (f32x4)0.f;
#pragma unroll
    for (int kk = 0; kk < 4; kk++) {
        int kbyte = kk * 64 + lk * 16;
        int arow = w * 16 + lrow;
        half8 af = *(const half8*)((const char*)Asw + arow * 256 + (kbyte ^ ((arow & 7) << 4)));
#pragma unroll
        for (int t = 0; t < 9; t++) {
            int n = t * 16 + lrow;
            half8 bf = *(const half8*)((const char*)Bsw + n * 256 + (kbyte ^ ((n & 7) << 4)));
            acc[t] = __builtin_amdgcn_mfma_f32_16x16x32_f16(af, bf, acc[t], 0, 0, 0);
        }
    }

    // --- epilogue: C[row][col], row=(lk*4+reg), col=lrow+16t; chunked store ---
    int row0 = brow + w * 16 + lk * 4;
#pragma unroll
    for (int r = 0; r < 4; r++) {
        int grow = row0 + r;
        if (grow < N_) {
#pragma unroll
            for (int t = 0; t < 8; t++) {
                // feature col = t*16 + lrow -> chunk t>>1, offset (t&1)*16 + lrow
                h16[((size_t)(t >> 1) * N_ + grow) * 32 + (t & 1) * 16 + lrow] =
                    __float2half(acc[t][r]);
            }
            if (lrow == 0) es[grow] = acc[8][r];
            else if (lrow == 1) ed[grow] = acc[8][r];
        }
    }
}

// ---------------- per-edge softmax weights (one wave per dst node) ----------------
// alpha[e] = exp(e_e - m) / z  (fp16), selfw[n] = exp(e_self - m) / z
__global__ __launch_bounds__(256) void alpha_compute(const float* __restrict__ es,
                                                     const float* __restrict__ ed,
                                                     const int* __restrict__ rowptr,
                                                     const int* __restrict__ col,
                                                     __half* __restrict__ alpha,
                                                     float* __restrict__ selfw) {
    int wv = threadIdx.x >> 6;
    int lane = threadIdx.x & 63;
    int node = blockIdx.x * 4 + wv;
    if (node >= N_) return;
    int beg = rowptr[node];
    int end = rowptr[node + 1];
    float edn = ed[node];
    float e_self = leaky(es[node] + edn);

    // chunk-0 edge per lane, cached in registers
    int i0 = beg + lane;
    float e0 = -INFINITY;
    if (i0 < end) e0 = leaky(es[col[i0]] + edn);

    float m = e0;
    for (int i = i0 + 64; i < end; i += 64) m = fmaxf(m, leaky(es[col[i]] + edn));
#pragma unroll
    for (int o = 32; o; o >>= 1) m = fmaxf(m, __shfl_xor(m, o));
    m = fmaxf(m, e_self);

    float w0 = (i0 < end) ? expf(e0 - m) : 0.f;
    float z = w0;
    for (int i = i0 + 64; i < end; i += 64) z += expf(leaky(es[col[i]] + edn) - m);
#pragma unroll
    for (int o = 32; o; o >>= 1) z += __shfl_xor(z, o);
    float ws = expf(e_self - m);
    z += ws;
    float inv = 1.0f / (z + 1e-16f);

    if (i0 < end) alpha[i0] = __float2half(w0 * inv);
    for (int i = i0 + 64; i < end; i += 64)
        alpha[i] = __float2half(expf(leaky(es[col[i]] + edn) - m) * inv);
    if (lane == 0) selfw[node] = ws * inv;
}

// ---------------- chunked gather-aggregate ----------------
// grid = 4 * ABLK; chunk = bid / ABLK (keeps one 3.2MB slice L2-resident).
// wave per node: 4 edge groups x 16 feature-lanes (4B = 2 halves each).
__global__ __launch_bounds__(256) void gat_gather(const __half* __restrict__ h16,
                                                  const __half* __restrict__ alpha,
                                                  const float* __restrict__ selfw,
                                                  const int* __restrict__ rowptr,
                                                  const int* __restrict__ col,
                                                  const float* __restrict__ bias,
                                                  __half* __restrict__ outc) {
    int chunk = blockIdx.x / ABLK;
    int nb = blockIdx.x - chunk * ABLK;
    int wv = threadIdx.x >> 6;
    int lane = threadIdx.x & 63;
    int node = nb * 4 + wv;
    if (node >= N_) return;
    int beg = rowptr[node];
    int deg = rowptr[node + 1] - beg;
    const __half* hc = h16 + (size_t)chunk * N_ * 32;

    int eg = lane >> 4;   // edge group 0..3
    int fl = lane & 15;   // feature pair: halves 2*fl, 2*fl+1 of the chunk

    float accx = 0.f, accy = 0.f;
#pragma unroll 2
    for (int j = eg; j < deg; j += 4) {
        int s = col[beg + j];                         // broadcast across 16 lanes
        float a = __half2float(alpha[beg + j]);
        float2 fv = __half22float2(*(const __half2*)(hc + (size_t)s * 32 + fl * 2));
        accx += a * fv.x;
        accy += a * fv.y;
    }
    // fold 4 edge groups
    accx += __shfl_xor(accx, 16); accx += __shfl_xor(accx, 32);
    accy += __shfl_xor(accy, 16); accy += __shfl_xor(accy, 32);

    if (eg == 0) {
        float sw = selfw[node];
        float2 sv = __half22float2(*(const __half2*)(hc + (size_t)node * 32 + fl * 2));
        float2 bv = *(const float2*)(bias + chunk * 32 + fl * 2);
        float v0 = fmaxf(accx + sw * sv.x + bv.x, 0.f);
        float v1 = fmaxf(accy + sw * sv.y + bv.y, 0.f);
        ((__half2*)(outc + ((size_t)chunk * N_ + node) * 32))[fl] = __floats2half2_rn(v0, v1);
    }
}

// ---------------- global max pool (chunked fp16 input) ----------------
__device__ __forceinline__ int lower_bound_batch(const int* __restrict__ batch, int val) {
    int lo = 0, hi = N_;
    while (lo < hi) {
        int mid = (lo + hi) >> 1;
        if (batch[mid] < val) lo = mid + 1;
        else hi = mid;
    }
    return lo;
}

__global__ __launch_bounds__(512) void pool_max(const __half* __restrict__ h16,
                                                const int* __restrict__ batch,
                                                float* __restrict__ gpool) {
    int g = blockIdx.x;
    int s = lower_bound_batch(batch, g);
    int e = lower_bound_batch(batch, g + 1);
    int f = threadIdx.x & 127;
    int rg = threadIdx.x >> 7;
    size_t cbase = (size_t)(f >> 5) * N_ * 32;
    int off = f & 31;
    float m = 0.f;  // h is post-ReLU (>=0), segments non-empty
    for (int i = s + rg; i < e; i += 4)
        m = fmaxf(m, __half2float(h16[cbase + (size_t)i * 32 + off]));
    __shared__ float red[4][128];
    red[rg][f] = m;
    __syncthreads();
    if (rg == 0) {
        m = fmaxf(fmaxf(red[0][f], red[1][f]), fmaxf(red[2][f], red[3][f]));
        gpool[g * 128 + f] = m;
    }
}

// ---------------- MLP head + log_softmax ----------------
__global__ __launch_bounds__(128) void head(const float* __restrict__ gpool,
                                            const float* __restrict__ W1,
                                            const float* __restrict__ b1,
                                            const float* __restrict__ W2,
                                            const float* __restrict__ b2,
                                            float* __restrict__ out) {
    int g = blockIdx.x;
    int t = threadIdx.x;
    __shared__ float gs[128], gp[128], lg[C_], lse;
    gs[t] = gpool[g * 128 + t];
    __syncthreads();
    float acc = b1[t];
#pragma unroll 8
    for (int k = 0; k < 128; k++) acc += gs[k] * W1[k * 128 + t];
    gp[t] = fmaxf(acc, 0.f);
    __syncthreads();
    if (t < C_) {
        float a2 = b2[t];
#pragma unroll 8
        for (int k = 0; k < 128; k++) a2 += gp[k] * W2[k * C_ + t];
        lg[t] = a2;
    }
    __syncthreads();
    if (t == 0) {
        float mm = lg[0];
#pragma unroll
        for (int i = 1; i < C_; i++) mm = fmaxf(mm, lg[i]);
        float ss = 0.f;
#pragma unroll
        for (int i = 0; i < C_; i++) ss += expf(lg[i] - mm);
        lse = mm + logf(ss);
    }
    __syncthreads();
    if (t < C_) out[g * C_ + t] = lg[t] - lse;
}

// ---------------- launch ----------------
extern "C" void kernel_launch(void* const* d_in, const int* in_sizes, int n_in,
                              void* d_out, int out_size, void* d_ws, size_t ws_size,
                              hipStream_t stream) {
    const float* x     = (const float*)d_in[0];
    const int*   eidx  = (const int*)d_in[1];
    const int*   batch = (const int*)d_in[2];
    const float* Wc    = (const float*)d_in[3];
    const float* a_src = (const float*)d_in[4];
    const float* a_dst = (const float*)d_in[5];
    const float* bc    = (const float*)d_in[6];
    const float* W1    = (const float*)d_in[7];
    const float* b1    = (const float*)d_in[8];
    const float* W2    = (const float*)d_in[9];
    const float* b2    = (const float*)d_in[10];
    float* out = (float*)d_out;

    const int* srcs = eidx;        // edge_index[0]
    const int* dsts = eidx + E_;   // edge_index[1]

    // workspace layout (16B-aligned segments)
    __half* hG16  = (__half*)d_ws;                    // [4][N][32] gemm out
    __half* hB16  = hG16 + (size_t)N_ * 128;          // [4][N][32] aggregate out
    float*  es    = (float*)(hB16 + (size_t)N_ * 128);// N
    float*  ed    = es + N_;                          // N
    float*  selfw = ed + N_;                          // N
    float*  gpool = selfw + N_;                       // G*128
    __half* Wt    = (__half*)(gpool + G_ * 128);      // 3*144*128
    __half* alpha = Wt + (size_t)3 * 144 * 128;       // E
    int*    rowptr = (int*)(alpha + E_);              // N+1
    int*    cnt   = rowptr + N_ + 1;                  // N
    int*    bsums = cnt + N_;                         // NBLK
    int*    col   = bsums + NBLK;                     // E

    // ---- weight prep + CSR build (CSR reused by all layers) ----
    prep_weights<<<L_, 256, 0, stream>>>(Wc, a_src, a_dst, Wt);
    zero_i32<<<(N_ + 1023) / 1024, 1024, 0, stream>>>(cnt, N_);
    count_deg<<<(E_ + 255) / 256, 256, 0, stream>>>(dsts, cnt);
    scan_block<<<NBLK, SCAN_B, 0, stream>>>(cnt, rowptr, bsums);
    scan_bsums<<<1, 256, 0, stream>>>(bsums, NBLK);
    add_offsets<<<NBLK, SCAN_B, 0, stream>>>(rowptr, bsums);
    zero_i32<<<(N_ + 1023) / 1024, 1024, 0, stream>>>(cnt, N_);
    fill_csr<<<(E_ + 255) / 256, 256, 0, stream>>>(srcs, dsts, rowptr, cnt, col);

    // ---- 3 GAT layers ----
    int gblk = (N_ + 63) / 64;
    gemm_mfma<false><<<gblk, 256, 0, stream>>>(x, Wt, hG16, es, ed);
    alpha_compute<<<ABLK, 256, 0, stream>>>(es, ed, rowptr, col, alpha, selfw);
    gat_gather<<<4 * ABLK, 256, 0, stream>>>(hG16, alpha, selfw, rowptr, col, bc, hB16);
    for (int l = 1; l < L_; ++l) {
        gemm_mfma<true><<<gblk, 256, 0, stream>>>(
            hB16, Wt + (size_t)l * 144 * 128, hG16, es, ed);
        alpha_compute<<<ABLK, 256, 0, stream>>>(es, ed, rowptr, col, alpha, selfw);
        gat_gather<<<4 * ABLK, 256, 0, stream>>>(hG16, alpha, selfw, rowptr, col,
                                                 bc + l * H_, hB16);
    }

    // ---- pool + head ----
    pool_max<<<G_, 512, 0, stream>>>(hB16, batch, gpool);
    head<<<G_, 128, 0, stream>>>(gpool, W1, b1, W2, b2, out);
}

// Round 8
// 275.729 us; speedup vs baseline: 1.5055x; 1.5055x over previous
//
#include <hip/hip_runtime.h>
#include <hip/hip_fp16.h>
#include <math.h>

#define N_ 50000
#define E_ 640000
#define H_ 128
#define L_ 3
#define G_ 256
#define C_ 10
#define NEG_SLOPE 0.2f

#define SCAN_B 256
#define NBLK ((N_ + SCAN_B - 1) / SCAN_B)   // 196
#define ABLK ((N_ + 3) / 4)                 // 12500 (4 nodes per block)

typedef _Float16 half8 __attribute__((ext_vector_type(8)));
typedef float f32x4 __attribute__((ext_vector_type(4)));

__device__ __forceinline__ float leaky(float x) { return x > 0.f ? x : NEG_SLOPE * x; }
// output position p holds feature pi_out(p); same for every layer's h16
__device__ __forceinline__ int pi_out(int p) { return ((p & 7) << 4) + (p >> 3); }

// ---------------- utility ----------------
__global__ void zero_i32(int* __restrict__ p, int n) {
    int i = blockIdx.x * blockDim.x + threadIdx.x;
    if (i < n) p[i] = 0;
}

// ---------------- CSR build (rowptr self-advancing; row d = [rp[d-1], rp[d])) ----------------
__global__ void count_deg(const int* __restrict__ dst, int* __restrict__ rowptr) {
    int i = blockIdx.x * blockDim.x + threadIdx.x;
    if (i < E_) atomicAdd(&rowptr[dst[i]], 1);
}

__global__ __launch_bounds__(SCAN_B) void scan_block(int* __restrict__ rowptr,
                                                     int* __restrict__ bsums) {
    int tid = threadIdx.x;
    int gid = blockIdx.x * SCAN_B + tid;
    int v = (gid < N_) ? rowptr[gid] : 0;
    int lane = tid & 63, wid = tid >> 6;
    int x = v;
#pragma unroll
    for (int o = 1; o < 64; o <<= 1) {
        int t = __shfl_up(x, o);
        if (lane >= o) x += t;
    }
    __shared__ int wsum[4];
    if (lane == 63) wsum[wid] = x;
    __syncthreads();
    int woff = 0;
    for (int i = 0; i < wid; i++) woff += wsum[i];
    int incl = x + woff;
    if (gid < N_) rowptr[gid] = incl - v;            // exclusive within block
    if (tid == SCAN_B - 1) bsums[blockIdx.x] = incl; // block total
}

__global__ __launch_bounds__(256) void scan_bsums(int* __restrict__ bsums, int nb) {
    int tid = threadIdx.x;
    int v = (tid < nb) ? bsums[tid] : 0;
    int lane = tid & 63, wid = tid >> 6;
    int x = v;
#pragma unroll
    for (int o = 1; o < 64; o <<= 1) {
        int t = __shfl_up(x, o);
        if (lane >= o) x += t;
    }
    __shared__ int wsum[4];
    if (lane == 63) wsum[wid] = x;
    __syncthreads();
    int woff = 0;
    for (int i = 0; i < wid; i++) woff += wsum[i];
    if (tid < nb) bsums[tid] = x + woff - v;         // exclusive
}

__global__ __launch_bounds__(SCAN_B) void add_offsets(int* __restrict__ rowptr,
                                                      const int* __restrict__ bsums) {
    int gid = blockIdx.x * SCAN_B + threadIdx.x;
    if (gid < N_) rowptr[gid] += bsums[blockIdx.x];
}

__global__ void fill_csr(const int* __restrict__ src, const int* __restrict__ dst,
                         int* __restrict__ rowptr, int* __restrict__ col) {
    int i = blockIdx.x * blockDim.x + threadIdx.x;
    if (i < E_) {
        int d = dst[i];
        int p = atomicAdd(&rowptr[d], 1);   // advances start -> end
        col[p] = src[i];
    }
}

// ---------------- weight prep: Wt[l][144][128] fp16 (k-dim permuted for l>=1) ----------------
// T[n*128+p] = W[ks(p)][n]; row 128: (W@a_src)[ks(p)]; row 129: (W@a_dst)[ks(p)];
// rows 130..143 zero. Also bcp[l][p] = bc[l][pi_out(p)].
__global__ __launch_bounds__(256) void prep_weights(const float* __restrict__ Wc,
                                                    const float* __restrict__ a_src,
                                                    const float* __restrict__ a_dst,
                                                    const float* __restrict__ bc,
                                                    __half* __restrict__ Wt,
                                                    float* __restrict__ bcp) {
    int l = blockIdx.x;
    const float* W = Wc + l * 16384;
    __half* T = Wt + (size_t)l * 144 * 128;
    int t = threadIdx.x;
    for (int e = t; e < 16384; e += 256) {
        int n = e >> 7, p = e & 127;
        int ks = (l == 0) ? p : pi_out(p);
        T[n * 128 + p] = __float2half(W[ks * 128 + n]);
    }
    if (t < 128) {
        int p = t;
        int ks = (l == 0) ? p : pi_out(p);
        const float* as = a_src + l * 128;
        const float* ad = a_dst + l * 128;
        float s = 0.f, d = 0.f;
#pragma unroll 8
        for (int n = 0; n < 128; n++) {
            float w = W[ks * 128 + n];
            s += w * as[n];
            d += w * ad[n];
        }
        T[128 * 128 + p] = __float2half(s);
        T[129 * 128 + p] = __float2half(d);
        bcp[l * 128 + p] = bc[l * 128 + pi_out(p)];
    } else {
        int kk = t - 128;
        for (int r = 130; r < 144; r++) T[r * 128 + kk] = __float2half(0.f);
    }
}

// ---------------- MFMA GEMM: h16 = fp16(A @ W) position-permuted, es/ed fused ----------------
// block = 256 threads (4 waves), BM=64 rows, N=128(+16) cols, K=128.
// LDS XOR-swizzled (byte ^= (row&7)<<4) for conflict-free ds_read_b128.
// Epilogue: lane stores its 8 cols contiguously -> position p = lrow*8 + t.
template <bool FP16IN>
__global__ __launch_bounds__(256) void gemm_mfma(const void* __restrict__ Av,
                                                 const __half* __restrict__ Wt,
                                                 __half* __restrict__ h16,
                                                 float* __restrict__ es,
                                                 float* __restrict__ ed) {
    __shared__ __half Asw[64 * 128];    // 16 KB
    __shared__ __half Bsw[144 * 128];   // 36 KB
    int tid = threadIdx.x;
    int brow = blockIdx.x * 64;

    // --- stage A (swizzled) ---
    {
        int r = tid >> 2;             // 0..63
        int q = tid & 3;              // 32-elem chunk
        int grow = brow + r;
        if (FP16IN) {
            const __half* Ah = (const __half*)Av;
            float4 vv[4];
            if (grow < N_) {
                const float4* p = (const float4*)(Ah + (size_t)grow * 128 + q * 32);
#pragma unroll
                for (int s = 0; s < 4; s++) vv[s] = p[s];
            } else {
                float4 zz = make_float4(0.f, 0.f, 0.f, 0.f);
#pragma unroll
                for (int s = 0; s < 4; s++) vv[s] = zz;
            }
#pragma unroll
            for (int s = 0; s < 4; s++) {
                int kbyte = q * 64 + s * 16;
                int addr = r * 256 + (kbyte ^ ((r & 7) << 4));
                *(float4*)((char*)Asw + addr) = vv[s];
            }
        } else {
            const float* A = (const float*)Av;
            int kc = q * 32;
            float v[32];
            if (grow < N_) {
                const float4* p = (const float4*)(A + (size_t)grow * 128 + kc);
#pragma unroll
                for (int s = 0; s < 8; s++) {
                    float4 f = p[s];
                    v[s * 4] = f.x; v[s * 4 + 1] = f.y; v[s * 4 + 2] = f.z; v[s * 4 + 3] = f.w;
                }
            } else {
#pragma unroll
                for (int s = 0; s < 32; s++) v[s] = 0.f;
            }
#pragma unroll
            for (int s = 0; s < 4; s++) {
                half8 h;
#pragma unroll
                for (int j = 0; j < 8; j++) h[j] = (_Float16)v[s * 8 + j];
                int kbyte = kc * 2 + s * 16;
                int addr = r * 256 + (kbyte ^ ((r & 7) << 4));
                *(half8*)((char*)Asw + addr) = h;
            }
        }
    }
    // --- stage B: linear fp16 copy, swizzled (2304 16B chunks) ---
    {
        const float4* src = (const float4*)Wt;
#pragma unroll
        for (int i = 0; i < 9; i++) {
            int c = tid + i * 256;
            int o = c * 16;
            int n = o >> 8;
            float4 val = src[c];
            int addr = n * 256 + ((o & 255) ^ ((n & 7) << 4));
            *(float4*)((char*)Bsw + addr) = val;
        }
    }
    __syncthreads();

    // --- MFMA: wave w -> rows w*16..+15, 9 n-tiles, 4 k-steps ---
    int w = tid >> 6, l = tid & 63;
    int lrow = l & 15, lk = l >> 4;
    f32x4 acc[9];
#pragma unroll
    for (int t = 0; t < 9; t++) acc[t] = (f32x4)0.f;
#pragma unroll
    for (int kk = 0; kk < 4; kk++) {
        int kbyte = kk * 64 + lk * 16;
        int arow = w * 16 + lrow;
        half8 af = *(const half8*)((const char*)Asw + arow * 256 + (kbyte ^ ((arow & 7) << 4)));
#pragma unroll
        for (int t = 0; t < 9; t++) {
            int n = t * 16 + lrow;
            half8 bf = *(const half8*)((const char*)Bsw + n * 256 + (kbyte ^ ((n & 7) << 4)));
            acc[t] = __builtin_amdgcn_mfma_f32_16x16x32_f16(af, bf, acc[t], 0, 0, 0);
        }
    }

    // --- epilogue: row=(lk*4+r), cols 16t+lrow stored contiguously at p=lrow*8+t ---
    int row0 = brow + w * 16 + lk * 4;
#pragma unroll
    for (int r = 0; r < 4; r++) {
        int grow = row0 + r;
        if (grow < N_) {
            half8 hv;
#pragma unroll
            for (int t = 0; t < 8; t++) hv[t] = (_Float16)acc[t][r];
            *(half8*)(h16 + (size_t)grow * 128 + lrow * 8) = hv;
            if (lrow == 0) es[grow] = acc[8][r];
            else if (lrow == 1) ed[grow] = acc[8][r];
        }
    }
}

// ---------------- per-edge softmax weights (one wave per dst node) ----------------
// packed[e] = col(u16) | alpha(fp16)<<16 ; selfw[n] = exp(e_self - m)/z
__global__ __launch_bounds__(256) void alpha_compute(const float* __restrict__ es,
                                                     const float* __restrict__ ed,
                                                     const int* __restrict__ rowptr,
                                                     const int* __restrict__ col,
                                                     unsigned int* __restrict__ packed,
                                                     float* __restrict__ selfw) {
    int wv = threadIdx.x >> 6;
    int lane = threadIdx.x & 63;
    int node = blockIdx.x * 4 + wv;
    if (node >= N_) return;
    int end = rowptr[node];
    int beg = node ? rowptr[node - 1] : 0;
    float edn = ed[node];
    float e_self = leaky(es[node] + edn);

    // chunk-0 edge per lane, cached in registers
    int i0 = beg + lane;
    int c0 = 0;
    float e0 = -INFINITY;
    if (i0 < end) { c0 = col[i0]; e0 = leaky(es[c0] + edn); }

    float m = e0;
    for (int i = i0 + 64; i < end; i += 64) m = fmaxf(m, leaky(es[col[i]] + edn));
#pragma unroll
    for (int o = 32; o; o >>= 1) m = fmaxf(m, __shfl_xor(m, o));
    m = fmaxf(m, e_self);

    float w0 = (i0 < end) ? expf(e0 - m) : 0.f;
    float z = w0;
    for (int i = i0 + 64; i < end; i += 64) z += expf(leaky(es[col[i]] + edn) - m);
#pragma unroll
    for (int o = 32; o; o >>= 1) z += __shfl_xor(z, o);
    float ws = expf(e_self - m);
    z += ws;
    float inv = 1.0f / (z + 1e-16f);

    if (i0 < end)
        packed[i0] = (unsigned int)c0 |
                     ((unsigned int)__half_as_ushort(__float2half(w0 * inv)) << 16);
    for (int i = i0 + 64; i < end; i += 64) {
        int c = col[i];
        float a = expf(leaky(es[c] + edn) - m) * inv;
        packed[i] = (unsigned int)c |
                    ((unsigned int)__half_as_ushort(__float2half(a)) << 16);
    }
    if (lane == 0) selfw[node] = ws * inv;
}

// ---------------- gather-aggregate (one wave per dst node) ----------------
// 4 edge groups x 16 feature-lanes; broadcast packed edge word; 16B row gathers.
__global__ __launch_bounds__(256) void gat_gather(const __half* __restrict__ h16,
                                                  const unsigned int* __restrict__ packed,
                                                  const float* __restrict__ selfw,
                                                  const int* __restrict__ rowptr,
                                                  const float* __restrict__ biasp,
                                                  __half* __restrict__ hout) {
    int wv = threadIdx.x >> 6;
    int lane = threadIdx.x & 63;
    int node = blockIdx.x * 4 + wv;
    if (node >= N_) return;
    int end = rowptr[node];
    int beg = node ? rowptr[node - 1] : 0;
    int deg = end - beg;

    int eg = lane >> 4;   // edge group 0..3
    int fl = lane & 15;   // 16-B slot: positions fl*8..fl*8+7

    float acc[8] = {0.f, 0.f, 0.f, 0.f, 0.f, 0.f, 0.f, 0.f};
    const unsigned int* pk = packed + beg;
#pragma unroll 2
    for (int j = eg; j < deg; j += 4) {
        unsigned int wd = pk[j];                      // broadcast across 16 lanes
        int s = wd & 0xFFFF;
        float a = __half2float(__ushort_as_half((unsigned short)(wd >> 16)));
        union { float4 f4; __half2 h2[4]; } u;
        u.f4 = *(const float4*)(h16 + (size_t)s * 128 + fl * 8);
#pragma unroll
        for (int q = 0; q < 4; q++) {
            float2 fv = __half22float2(u.h2[q]);
            acc[2 * q]     += a * fv.x;
            acc[2 * q + 1] += a * fv.y;
        }
    }
    // fold 4 edge groups
#pragma unroll
    for (int q = 0; q < 8; q++) {
        acc[q] += __shfl_xor(acc[q], 16);
        acc[q] += __shfl_xor(acc[q], 32);
    }

    if (eg == 0) {
        float sw = selfw[node];
        union { float4 f4; __half2 h2[4]; } su;
        su.f4 = *(const float4*)(h16 + (size_t)node * 128 + fl * 8);
        const float4* bp = (const float4*)(biasp + fl * 8);
        float4 b0 = bp[0], b1 = bp[1];
        float bq[8] = {b0.x, b0.y, b0.z, b0.w, b1.x, b1.y, b1.z, b1.w};
        union { float4 f4; __half2 h2[4]; } ou;
#pragma unroll
        for (int q = 0; q < 4; q++) {
            float2 sv = __half22float2(su.h2[q]);
            float v0 = fmaxf(acc[2 * q]     + sw * sv.x + bq[2 * q],     0.f);
            float v1 = fmaxf(acc[2 * q + 1] + sw * sv.y + bq[2 * q + 1], 0.f);
            ou.h2[q] = __floats2half2_rn(v0, v1);
        }
        *(float4*)(hout + (size_t)node * 128 + fl * 8) = ou.f4;
    }
}

// ---------------- global max pool (fp16 [N][128], position order) ----------------
__device__ __forceinline__ int lower_bound_batch(const int* __restrict__ batch, int val) {
    int lo = 0, hi = N_;
    while (lo < hi) {
        int mid = (lo + hi) >> 1;
        if (batch[mid] < val) lo = mid + 1;
        else hi = mid;
    }
    return lo;
}

__global__ __launch_bounds__(512) void pool_max(const __half* __restrict__ h16,
                                                const int* __restrict__ batch,
                                                float* __restrict__ gpool) {
    int g = blockIdx.x;
    int s = lower_bound_batch(batch, g);
    int e = lower_bound_batch(batch, g + 1);
    int f = threadIdx.x & 127;
    int rg = threadIdx.x >> 7;
    float m = 0.f;  // h is post-ReLU (>=0), segments non-empty
    for (int i = s + rg; i < e; i += 4)
        m = fmaxf(m, __half2float(h16[(size_t)i * 128 + f]));
    __shared__ float red[4][128];
    red[rg][f] = m;
    __syncthreads();
    if (rg == 0) {
        m = fmaxf(fmaxf(red[0][f], red[1][f]), fmaxf(red[2][f], red[3][f]));
        gpool[g * 128 + f] = m;   // position order; head unpermutes
    }
}

// ---------------- MLP head + log_softmax (unpermutes gpool positions) ----------------
__global__ __launch_bounds__(128) void head(const float* __restrict__ gpool,
                                            const float* __restrict__ W1,
                                            const float* __restrict__ b1,
                                            const float* __restrict__ W2,
                                            const float* __restrict__ b2,
                                            float* __restrict__ out) {
    int g = blockIdx.x;
    int t = threadIdx.x;
    __shared__ float gs[128], gp[128], lg[C_], lse;
    gs[t] = gpool[g * 128 + t];
    __syncthreads();
    float acc = b1[t];
#pragma unroll 8
    for (int k = 0; k < 128; k++) {
        int f = pi_out(k);  // feature stored at position k
        acc += gs[k] * W1[f * 128 + t];
    }
    gp[t] = fmaxf(acc, 0.f);
    __syncthreads();
    if (t < C_) {
        float a2 = b2[t];
#pragma unroll 8
        for (int k = 0; k < 128; k++) a2 += gp[k] * W2[k * C_ + t];
        lg[t] = a2;
    }
    __syncthreads();
    if (t == 0) {
        float mm = lg[0];
#pragma unroll
        for (int i = 1; i < C_; i++) mm = fmaxf(mm, lg[i]);
        float ss = 0.f;
#pragma unroll
        for (int i = 0; i < C_; i++) ss += expf(lg[i] - mm);
        lse = mm + logf(ss);
    }
    __syncthreads();
    if (t < C_) out[g * C_ + t] = lg[t] - lse;
}

// ---------------- launch ----------------
extern "C" void kernel_launch(void* const* d_in, const int* in_sizes, int n_in,
                              void* d_out, int out_size, void* d_ws, size_t ws_size,
                              hipStream_t stream) {
    const float* x     = (const float*)d_in[0];
    const int*   eidx  = (const int*)d_in[1];
    const int*   batch = (const int*)d_in[2];
    const float* Wc    = (const float*)d_in[3];
    const float* a_src = (const float*)d_in[4];
    const float* a_dst = (const float*)d_in[5];
    const float* bc    = (const float*)d_in[6];
    const float* W1    = (const float*)d_in[7];
    const float* b1    = (const float*)d_in[8];
    const float* W2    = (const float*)d_in[9];
    const float* b2    = (const float*)d_in[10];
    float* out = (float*)d_out;

    const int* srcs = eidx;        // edge_index[0]
    const int* dsts = eidx + E_;   // edge_index[1]

    // workspace layout (16B-aligned segments)
    __half* hG16  = (__half*)d_ws;                      // [N][128] gemm out (permuted)
    __half* hB16  = hG16 + (size_t)N_ * 128;            // [N][128] aggregate out
    float*  es    = (float*)(hB16 + (size_t)N_ * 128);  // N
    float*  ed    = es + N_;                            // N
    float*  selfw = ed + N_;                            // N
    float*  gpool = selfw + N_;                         // G*128
    float*  bcp   = gpool + G_ * 128;                   // 3*128
    __half* Wt    = (__half*)(bcp + 3 * 128);           // 3*144*128
    unsigned int* packed = (unsigned int*)(Wt + (size_t)3 * 144 * 128); // E
    int*    rowptr = (int*)(packed + E_);               // N
    int*    bsums = rowptr + N_;                        // NBLK
    int*    col   = bsums + NBLK;                       // E

    // ---- weight prep + CSR build (CSR reused by all layers) ----
    prep_weights<<<L_, 256, 0, stream>>>(Wc, a_src, a_dst, bc, Wt, bcp);
    zero_i32<<<(N_ + 1023) / 1024, 1024, 0, stream>>>(rowptr, N_);
    count_deg<<<(E_ + 255) / 256, 256, 0, stream>>>(dsts, rowptr);
    scan_block<<<NBLK, SCAN_B, 0, stream>>>(rowptr, bsums);
    scan_bsums<<<1, 256, 0, stream>>>(bsums, NBLK);
    add_offsets<<<NBLK, SCAN_B, 0, stream>>>(rowptr, bsums);
    fill_csr<<<(E_ + 255) / 256, 256, 0, stream>>>(srcs, dsts, rowptr, col);
    // after fill: rowptr[d] = end of row d; row d = [rowptr[d-1], rowptr[d])

    // ---- 3 GAT layers ----
    int gblk = (N_ + 63) / 64;
    gemm_mfma<false><<<gblk, 256, 0, stream>>>(x, Wt, hG16, es, ed);
    alpha_compute<<<ABLK, 256, 0, stream>>>(es, ed, rowptr, col, packed, selfw);
    gat_gather<<<ABLK, 256, 0, stream>>>(hG16, packed, selfw, rowptr, bcp, hB16);
    for (int l = 1; l < L_; ++l) {
        gemm_mfma<true><<<gblk, 256, 0, stream>>>(
            hB16, Wt + (size_t)l * 144 * 128, hG16, es, ed);
        alpha_compute<<<ABLK, 256, 0, stream>>>(es, ed, rowptr, col, packed, selfw);
        gat_gather<<<ABLK, 256, 0, stream>>>(hG16, packed, selfw, rowptr,
                                             bcp + l * 128, hB16);
    }

    // ---- pool + head ----
    pool_max<<<G_, 512, 0, stream>>>(hB16, batch, gpool);
    head<<<G_, 128, 0, stream>>>(gpool, W1, b1, W2, b2, out);
}

// Round 9
// 241.514 us; speedup vs baseline: 1.7188x; 1.1417x over previous
//
#include <hip/hip_runtime.h>
#include <hip/hip_fp16.h>
#include <math.h>

#define N_ 50000
#define E_ 640000
#define H_ 128
#define L_ 3
#define G_ 256
#define C_ 10
#define NEG_SLOPE 0.2f

#define SCAN_B 256
#define NBLK ((N_ + SCAN_B - 1) / SCAN_B)   // 196
#define ABLK ((N_ + 3) / 4)                 // 12500 (4 nodes per block)

typedef _Float16 half8 __attribute__((ext_vector_type(8)));
typedef float f32x4 __attribute__((ext_vector_type(4)));

__device__ __forceinline__ float leaky(float x) { return x > 0.f ? x : NEG_SLOPE * x; }
// output position p holds feature pi_out(p); same for every layer's h16
__device__ __forceinline__ int pi_out(int p) { return ((p & 7) << 4) + (p >> 3); }

// ---------------- utility ----------------
__global__ void zero_i32(int* __restrict__ p, int n) {
    int i = blockIdx.x * blockDim.x + threadIdx.x;
    if (i < n) p[i] = 0;
}

// ---------------- CSR build (rowptr self-advancing; row d = [rp[d-1], rp[d])) ----------------
__global__ void count_deg(const int* __restrict__ dst, int* __restrict__ rowptr) {
    int i = blockIdx.x * blockDim.x + threadIdx.x;
    if (i < E_) atomicAdd(&rowptr[dst[i]], 1);
}

__global__ __launch_bounds__(SCAN_B) void scan_block(int* __restrict__ rowptr,
                                                     int* __restrict__ bsums) {
    int tid = threadIdx.x;
    int gid = blockIdx.x * SCAN_B + tid;
    int v = (gid < N_) ? rowptr[gid] : 0;
    int lane = tid & 63, wid = tid >> 6;
    int x = v;
#pragma unroll
    for (int o = 1; o < 64; o <<= 1) {
        int t = __shfl_up(x, o);
        if (lane >= o) x += t;
    }
    __shared__ int wsum[4];
    if (lane == 63) wsum[wid] = x;
    __syncthreads();
    int woff = 0;
    for (int i = 0; i < wid; i++) woff += wsum[i];
    int incl = x + woff;
    if (gid < N_) rowptr[gid] = incl - v;            // exclusive within block
    if (tid == SCAN_B - 1) bsums[blockIdx.x] = incl; // block total
}

__global__ __launch_bounds__(256) void scan_bsums(int* __restrict__ bsums, int nb) {
    int tid = threadIdx.x;
    int v = (tid < nb) ? bsums[tid] : 0;
    int lane = tid & 63, wid = tid >> 6;
    int x = v;
#pragma unroll
    for (int o = 1; o < 64; o <<= 1) {
        int t = __shfl_up(x, o);
        if (lane >= o) x += t;
    }
    __shared__ int wsum[4];
    if (lane == 63) wsum[wid] = x;
    __syncthreads();
    int woff = 0;
    for (int i = 0; i < wid; i++) woff += wsum[i];
    if (tid < nb) bsums[tid] = x + woff - v;         // exclusive
}

__global__ __launch_bounds__(SCAN_B) void add_offsets(int* __restrict__ rowptr,
                                                      const int* __restrict__ bsums) {
    int gid = blockIdx.x * SCAN_B + threadIdx.x;
    if (gid < N_) rowptr[gid] += bsums[blockIdx.x];
}

__global__ void fill_csr(const int* __restrict__ src, const int* __restrict__ dst,
                         int* __restrict__ rowptr, int* __restrict__ col) {
    int i = blockIdx.x * blockDim.x + threadIdx.x;
    if (i < E_) {
        int d = dst[i];
        int p = atomicAdd(&rowptr[d], 1);   // advances start -> end
        col[p] = src[i];
    }
}

// ---------------- weight prep: Wt[l][144][128] fp16 (k-dim permuted for l>=1) ----------------
// T[n*128+p] = W[ks(p)][n]; row 128: (W@a_src)[ks(p)]; row 129: (W@a_dst)[ks(p)];
// rows 130..143 zero. Also bcp[l][p] = bc[l][pi_out(p)].
__global__ __launch_bounds__(256) void prep_weights(const float* __restrict__ Wc,
                                                    const float* __restrict__ a_src,
                                                    const float* __restrict__ a_dst,
                                                    const float* __restrict__ bc,
                                                    __half* __restrict__ Wt,
                                                    float* __restrict__ bcp) {
    int l = blockIdx.x;
    const float* W = Wc + l * 16384;
    __half* T = Wt + (size_t)l * 144 * 128;
    int t = threadIdx.x;
    for (int e = t; e < 16384; e += 256) {
        int n = e >> 7, p = e & 127;
        int ks = (l == 0) ? p : pi_out(p);
        T[n * 128 + p] = __float2half(W[ks * 128 + n]);
    }
    if (t < 128) {
        int p = t;
        int ks = (l == 0) ? p : pi_out(p);
        const float* as = a_src + l * 128;
        const float* ad = a_dst + l * 128;
        float s = 0.f, d = 0.f;
#pragma unroll 8
        for (int n = 0; n < 128; n++) {
            float w = W[ks * 128 + n];
            s += w * as[n];
            d += w * ad[n];
        }
        T[128 * 128 + p] = __float2half(s);
        T[129 * 128 + p] = __float2half(d);
        bcp[l * 128 + p] = bc[l * 128 + pi_out(p)];
    } else {
        int kk = t - 128;
        for (int r = 130; r < 144; r++) T[r * 128 + kk] = __float2half(0.f);
    }
}

// ---------------- MFMA GEMM: h16 = fp16(A @ W) position-permuted, es/ed fused ----------------
// block = 256 threads (4 waves), BM=64 rows, N=128(+16) cols, K=128.
// LDS XOR-swizzled (byte ^= (row&7)<<4) for conflict-free ds_read_b128.
// Epilogue: lane stores its 8 cols contiguously -> position p = lrow*8 + t.
template <bool FP16IN>
__global__ __launch_bounds__(256) void gemm_mfma(const void* __restrict__ Av,
                                                 const __half* __restrict__ Wt,
                                                 __half* __restrict__ h16,
                                                 float* __restrict__ es,
                                                 float* __restrict__ ed) {
    __shared__ __half Asw[64 * 128];    // 16 KB
    __shared__ __half Bsw[144 * 128];   // 36 KB
    int tid = threadIdx.x;
    int brow = blockIdx.x * 64;

    // --- stage A (swizzled) ---
    {
        int r = tid >> 2;             // 0..63
        int q = tid & 3;              // 32-elem chunk
        int grow = brow + r;
        if (FP16IN) {
            const __half* Ah = (const __half*)Av;
            float4 vv[4];
            if (grow < N_) {
                const float4* p = (const float4*)(Ah + (size_t)grow * 128 + q * 32);
#pragma unroll
                for (int s = 0; s < 4; s++) vv[s] = p[s];
            } else {
                float4 zz = make_float4(0.f, 0.f, 0.f, 0.f);
#pragma unroll
                for (int s = 0; s < 4; s++) vv[s] = zz;
            }
#pragma unroll
            for (int s = 0; s < 4; s++) {
                int kbyte = q * 64 + s * 16;
                int addr = r * 256 + (kbyte ^ ((r & 7) << 4));
                *(float4*)((char*)Asw + addr) = vv[s];
            }
        } else {
            const float* A = (const float*)Av;
            int kc = q * 32;
            float v[32];
            if (grow < N_) {
                const float4* p = (const float4*)(A + (size_t)grow * 128 + kc);
#pragma unroll
                for (int s = 0; s < 8; s++) {
                    float4 f = p[s];
                    v[s * 4] = f.x; v[s * 4 + 1] = f.y; v[s * 4 + 2] = f.z; v[s * 4 + 3] = f.w;
                }
            } else {
#pragma unroll
                for (int s = 0; s < 32; s++) v[s] = 0.f;
            }
#pragma unroll
            for (int s = 0; s < 4; s++) {
                half8 h;
#pragma unroll
                for (int j = 0; j < 8; j++) h[j] = (_Float16)v[s * 8 + j];
                int kbyte = kc * 2 + s * 16;
                int addr = r * 256 + (kbyte ^ ((r & 7) << 4));
                *(half8*)((char*)Asw + addr) = h;
            }
        }
    }
    // --- stage B: linear fp16 copy, swizzled (2304 16B chunks) ---
    {
        const float4* src = (const float4*)Wt;
#pragma unroll
        for (int i = 0; i < 9; i++) {
            int c = tid + i * 256;
            int o = c * 16;
            int n = o >> 8;
            float4 val = src[c];
            int addr = n * 256 + ((o & 255) ^ ((n & 7) << 4));
            *(float4*)((char*)Bsw + addr) = val;
        }
    }
    __syncthreads();

    // --- MFMA: wave w -> rows w*16..+15, 9 n-tiles, 4 k-steps ---
    int w = tid >> 6, l = tid & 63;
    int lrow = l & 15, lk = l >> 4;
    f32x4 acc[9];
#pragma unroll
    for (int t = 0; t < 9; t++) acc[t] = (f32x4)0.f;
#pragma unroll
    for (int kk = 0; kk < 4; kk++) {
        int kbyte = kk * 64 + lk * 16;
        int arow = w * 16 + lrow;
        half8 af = *(const half8*)((const char*)Asw + arow * 256 + (kbyte ^ ((arow & 7) << 4)));
#pragma unroll
        for (int t = 0; t < 9; t++) {
            int n = t * 16 + lrow;
            half8 bf = *(const half8*)((const char*)Bsw + n * 256 + (kbyte ^ ((n & 7) << 4)));
            acc[t] = __builtin_amdgcn_mfma_f32_16x16x32_f16(af, bf, acc[t], 0, 0, 0);
        }
    }

    // --- epilogue: row=(lk*4+r), cols 16t+lrow stored contiguously at p=lrow*8+t ---
    int row0 = brow + w * 16 + lk * 4;
#pragma unroll
    for (int r = 0; r < 4; r++) {
        int grow = row0 + r;
        if (grow < N_) {
            half8 hv;
#pragma unroll
            for (int t = 0; t < 8; t++) hv[t] = (_Float16)acc[t][r];
            *(half8*)(h16 + (size_t)grow * 128 + lrow * 8) = hv;
            if (lrow == 0) es[grow] = acc[8][r];
            else if (lrow == 1) ed[grow] = acc[8][r];
        }
    }
}

// ---------------- fused edge-softmax + gather-aggregate (one wave per dst node) ----------------
// No max-subtraction (logits clamped at 30; exp(30)=1e13 << fp32 max, z safe).
// chunk-0 cols/weights in registers -> LDS; agg: 4 edge groups x 16 feature-lanes,
// 16B row gathers, fp32 accum, fold via shfl_xor(16,32); fp16 output.
__global__ __launch_bounds__(256) void gat_aggregate(const __half* __restrict__ h16,
                                                     const float* __restrict__ es,
                                                     const float* __restrict__ ed,
                                                     const int* __restrict__ rowptr,
                                                     const int* __restrict__ col,
                                                     const float* __restrict__ biasp,
                                                     __half* __restrict__ hout) {
    __shared__ int   lds_s[4][64];
    __shared__ float lds_w[4][64];
    int wv = threadIdx.x >> 6;
    int lane = threadIdx.x & 63;
    int node = blockIdx.x * 4 + wv;
    if (node >= N_) return;
    int end = rowptr[node];
    int beg = node ? rowptr[node - 1] : 0;
    int deg = end - beg;
    float edn = ed[node];

    // chunk-0 edge per lane; unnormalized weights
    int i0 = beg + lane;
    int c0 = 0;
    float w0 = 0.f;
    if (i0 < end) {
        c0 = col[i0];
        w0 = expf(fminf(leaky(es[c0] + edn), 30.f));
    }
    float z = w0;
    for (int i = i0 + 64; i < end; i += 64)
        z += expf(fminf(leaky(es[col[i]] + edn), 30.f));
#pragma unroll
    for (int o = 32; o; o >>= 1) z += __shfl_xor(z, o);
    float ws = expf(fminf(leaky(es[node] + edn), 30.f));  // self-loop
    z += ws;
    float inv = 1.0f / (z + 1e-16f);

    lds_s[wv][lane] = c0;
    lds_w[wv][lane] = w0 * inv;   // pre-normalized alpha
    float sw = ws * inv;

    int eg = lane >> 4;   // edge group 0..3
    int fl = lane & 15;   // 16-B slot: positions fl*8..fl*8+7

    float acc[8] = {0.f, 0.f, 0.f, 0.f, 0.f, 0.f, 0.f, 0.f};
    int nl = min(deg, 64);
#pragma unroll 2
    for (int j = eg; j < nl; j += 4) {
        int s = lds_s[wv][j];                          // broadcast across 16 lanes
        float a = lds_w[wv][j];
        union { float4 f4; __half2 h2[4]; } u;
        u.f4 = *(const float4*)(h16 + (size_t)s * 128 + fl * 8);
#pragma unroll
        for (int q = 0; q < 4; q++) {
            float2 fv = __half22float2(u.h2[q]);
            acc[2 * q]     += a * fv.x;
            acc[2 * q + 1] += a * fv.y;
        }
    }
    // rare: degree > 64
    for (int cb = beg + 64; cb < end; cb += 64) {
        int idx = cb + lane;
        int cs = 0; float cw = 0.f;
        if (idx < end) {
            cs = col[idx];
            cw = expf(fminf(leaky(es[cs] + edn), 30.f)) * inv;
        }
        lds_s[wv][lane] = cs;
        lds_w[wv][lane] = cw;
        int n2 = min(end - cb, 64);
        for (int j = eg; j < n2; j += 4) {
            int s = lds_s[wv][j];
            float a = lds_w[wv][j];
            union { float4 f4; __half2 h2[4]; } u;
            u.f4 = *(const float4*)(h16 + (size_t)s * 128 + fl * 8);
#pragma unroll
            for (int q = 0; q < 4; q++) {
                float2 fv = __half22float2(u.h2[q]);
                acc[2 * q]     += a * fv.x;
                acc[2 * q + 1] += a * fv.y;
            }
        }
    }

    // fold the 4 edge groups
#pragma unroll
    for (int q = 0; q < 8; q++) {
        acc[q] += __shfl_xor(acc[q], 16);
        acc[q] += __shfl_xor(acc[q], 32);
    }

    if (eg == 0) {
        union { float4 f4; __half2 h2[4]; } su;
        su.f4 = *(const float4*)(h16 + (size_t)node * 128 + fl * 8);
        const float4* bp = (const float4*)(biasp + fl * 8);
        float4 b0 = bp[0], b1 = bp[1];
        float bq[8] = {b0.x, b0.y, b0.z, b0.w, b1.x, b1.y, b1.z, b1.w};
        union { float4 f4; __half2 h2[4]; } ou;
#pragma unroll
        for (int q = 0; q < 4; q++) {
            float2 sv = __half22float2(su.h2[q]);
            float v0 = fmaxf(acc[2 * q]     + sw * sv.x + bq[2 * q],     0.f);
            float v1 = fmaxf(acc[2 * q + 1] + sw * sv.y + bq[2 * q + 1], 0.f);
            ou.h2[q] = __floats2half2_rn(v0, v1);
        }
        *(float4*)(hout + (size_t)node * 128 + fl * 8) = ou.f4;
    }
}

// ---------------- global max pool (fp16 [N][128], position order) ----------------
__device__ __forceinline__ int lower_bound_batch(const int* __restrict__ batch, int val) {
    int lo = 0, hi = N_;
    while (lo < hi) {
        int mid = (lo + hi) >> 1;
        if (batch[mid] < val) lo = mid + 1;
        else hi = mid;
    }
    return lo;
}

__global__ __launch_bounds__(512) void pool_max(const __half* __restrict__ h16,
                                                const int* __restrict__ batch,
                                                float* __restrict__ gpool) {
    int g = blockIdx.x;
    int s = lower_bound_batch(batch, g);
    int e = lower_bound_batch(batch, g + 1);
    int f = threadIdx.x & 127;
    int rg = threadIdx.x >> 7;
    float m = 0.f;  // h is post-ReLU (>=0), segments non-empty
    for (int i = s + rg; i < e; i += 4)
        m = fmaxf(m, __half2float(h16[(size_t)i * 128 + f]));
    __shared__ float red[4][128];
    red[rg][f] = m;
    __syncthreads();
    if (rg == 0) {
        m = fmaxf(fmaxf(red[0][f], red[1][f]), fmaxf(red[2][f], red[3][f]));
        gpool[g * 128 + f] = m;   // position order; head unpermutes
    }
}

// ---------------- MLP head + log_softmax (unpermutes gpool positions) ----------------
__global__ __launch_bounds__(128) void head(const float* __restrict__ gpool,
                                            const float* __restrict__ W1,
                                            const float* __restrict__ b1,
                                            const float* __restrict__ W2,
                                            const float* __restrict__ b2,
                                            float* __restrict__ out) {
    int g = blockIdx.x;
    int t = threadIdx.x;
    __shared__ float gs[128], gp[128], lg[C_], lse;
    gs[t] = gpool[g * 128 + t];
    __syncthreads();
    float acc = b1[t];
#pragma unroll 8
    for (int k = 0; k < 128; k++) {
        int f = pi_out(k);  // feature stored at position k
        acc += gs[k] * W1[f * 128 + t];
    }
    gp[t] = fmaxf(acc, 0.f);
    __syncthreads();
    if (t < C_) {
        float a2 = b2[t];
#pragma unroll 8
        for (int k = 0; k < 128; k++) a2 += gp[k] * W2[k * C_ + t];
        lg[t] = a2;
    }
    __syncthreads();
    if (t == 0) {
        float mm = lg[0];
#pragma unroll
        for (int i = 1; i < C_; i++) mm = fmaxf(mm, lg[i]);
        float ss = 0.f;
#pragma unroll
        for (int i = 0; i < C_; i++) ss += expf(lg[i] - mm);
        lse = mm + logf(ss);
    }
    __syncthreads();
    if (t < C_) out[g * C_ + t] = lg[t] - lse;
}

// ---------------- launch ----------------
extern "C" void kernel_launch(void* const* d_in, const int* in_sizes, int n_in,
                              void* d_out, int out_size, void* d_ws, size_t ws_size,
                              hipStream_t stream) {
    const float* x     = (const float*)d_in[0];
    const int*   eidx  = (const int*)d_in[1];
    const int*   batch = (const int*)d_in[2];
    const float* Wc    = (const float*)d_in[3];
    const float* a_src = (const float*)d_in[4];
    const float* a_dst = (const float*)d_in[5];
    const float* bc    = (const float*)d_in[6];
    const float* W1    = (const float*)d_in[7];
    const float* b1    = (const float*)d_in[8];
    const float* W2    = (const float*)d_in[9];
    const float* b2    = (const float*)d_in[10];
    float* out = (float*)d_out;

    const int* srcs = eidx;        // edge_index[0]
    const int* dsts = eidx + E_;   // edge_index[1]

    // workspace layout (16B-aligned segments)
    __half* hG16  = (__half*)d_ws;                      // [N][128] gemm out (permuted)
    __half* hB16  = hG16 + (size_t)N_ * 128;            // [N][128] aggregate out
    float*  es    = (float*)(hB16 + (size_t)N_ * 128);  // N
    float*  ed    = es + N_;                            // N
    float*  gpool = ed + N_;                            // G*128
    float*  bcp   = gpool + G_ * 128;                   // 3*128
    __half* Wt    = (__half*)(bcp + 3 * 128);           // 3*144*128
    int*    rowptr = (int*)(Wt + (size_t)3 * 144 * 128);// N
    int*    bsums = rowptr + N_;                        // NBLK
    int*    col   = bsums + NBLK;                       // E

    // ---- weight prep + CSR build (CSR reused by all layers) ----
    prep_weights<<<L_, 256, 0, stream>>>(Wc, a_src, a_dst, bc, Wt, bcp);
    zero_i32<<<(N_ + 1023) / 1024, 1024, 0, stream>>>(rowptr, N_);
    count_deg<<<(E_ + 255) / 256, 256, 0, stream>>>(dsts, rowptr);
    scan_block<<<NBLK, SCAN_B, 0, stream>>>(rowptr, bsums);
    scan_bsums<<<1, 256, 0, stream>>>(bsums, NBLK);
    add_offsets<<<NBLK, SCAN_B, 0, stream>>>(rowptr, bsums);
    fill_csr<<<(E_ + 255) / 256, 256, 0, stream>>>(srcs, dsts, rowptr, col);
    // after fill: rowptr[d] = end of row d; row d = [rowptr[d-1], rowptr[d])

    // ---- 3 GAT layers ----
    int gblk = (N_ + 63) / 64;
    gemm_mfma<false><<<gblk, 256, 0, stream>>>(x, Wt, hG16, es, ed);
    gat_aggregate<<<ABLK, 256, 0, stream>>>(hG16, es, ed, rowptr, col, bcp, hB16);
    for (int l = 1; l < L_; ++l) {
        gemm_mfma<true><<<gblk, 256, 0, stream>>>(
            hB16, Wt + (size_t)l * 144 * 128, hG16, es, ed);
        gat_aggregate<<<ABLK, 256, 0, stream>>>(hG16, es, ed, rowptr, col,
                                                bcp + l * 128, hB16);
    }

    // ---- pool + head ----
    pool_max<<<G_, 512, 0, stream>>>(hB16, batch, gpool);
    head<<<G_, 128, 0, stream>>>(gpool, W1, b1, W2, b2, out);
}